// Round 1
// baseline (105.148 us; speedup 1.0000x reference)
//
#include <hip/hip_runtime.h>
#include <hip/hip_bf16.h>

typedef __attribute__((ext_vector_type(8))) short short8;
typedef __attribute__((ext_vector_type(4))) float f32x4;
typedef unsigned short u16;
typedef unsigned int u32;

#define NROWS 8192
#define HALF  4096
#define DIM   256
#define TEMP_INV 2.0f   // 1/temperature
#define BK 64

__device__ __forceinline__ float bf2f(u16 u) {
    union { u32 i; float f; } c; c.i = ((u32)u) << 16; return c.f;
}
__device__ __forceinline__ u16 f2bf(float f) {
    union { float f; u32 i; } c; c.f = f;
    u32 lsb = (c.i >> 16) & 1;
    c.i += 0x7fffu + lsb;   // round-to-nearest-even
    return (u16)(c.i >> 16);
}

// ---------------- kernel 1: normalize rows, write bf16, zero denom ----------
__global__ __launch_bounds__(256) void normalize_k(const float* __restrict__ zi,
                                                   const float* __restrict__ zj,
                                                   u16* __restrict__ zn,
                                                   float* __restrict__ denom) {
    const int row  = blockIdx.x * 4 + (threadIdx.x >> 6);
    const int lane = threadIdx.x & 63;
    const float* src = (row < HALF) ? (zi + (size_t)row * DIM)
                                    : (zj + (size_t)(row - HALF) * DIM);
    float4 v = reinterpret_cast<const float4*>(src)[lane];
    float ss = v.x * v.x + v.y * v.y + v.z * v.z + v.w * v.w;
    #pragma unroll
    for (int m = 32; m; m >>= 1) ss += __shfl_xor(ss, m);
    const float inv = 1.0f / fmaxf(sqrtf(ss), 1e-8f);
    ushort4 o;
    o.x = f2bf(v.x * inv); o.y = f2bf(v.y * inv);
    o.z = f2bf(v.z * inv); o.w = f2bf(v.w * inv);
    reinterpret_cast<ushort4*>(zn + (size_t)row * DIM)[lane] = o;
    if (lane == 0) denom[row] = 0.0f;
}

// ---------------- kernel 2: positives + self-sim (for diagonal removal) -----
__global__ __launch_bounds__(256) void posself_k(const u16* __restrict__ zn,
                                                 float* __restrict__ pos,
                                                 float* __restrict__ selfs) {
    const int row  = blockIdx.x * 4 + (threadIdx.x >> 6);
    const int lane = threadIdx.x & 63;
    const int partner = (row + HALF) & (NROWS - 1);
    ushort4 a = reinterpret_cast<const ushort4*>(zn + (size_t)row * DIM)[lane];
    ushort4 b = reinterpret_cast<const ushort4*>(zn + (size_t)partner * DIM)[lane];
    const float ax = bf2f(a.x), ay = bf2f(a.y), az = bf2f(a.z), aw = bf2f(a.w);
    float dp = ax * bf2f(b.x) + ay * bf2f(b.y) + az * bf2f(b.z) + aw * bf2f(b.w);
    float ds = ax * ax + ay * ay + az * az + aw * aw;
    #pragma unroll
    for (int m = 32; m; m >>= 1) { dp += __shfl_xor(dp, m); ds += __shfl_xor(ds, m); }
    if (lane == 0) { pos[row] = dp; selfs[row] = ds; }
}

// ---------------- kernel 3: fused GEMM + exp + row-sum ----------------------
__device__ __forceinline__ void gload16(const void* g, void* lds) {
    __builtin_amdgcn_global_load_lds(
        (const __attribute__((address_space(1))) u32*)g,
        (__attribute__((address_space(3))) u32*)lds, 16, 0, 0);
}

__global__ __launch_bounds__(256) void gemm_exp_rowsum(const u16* __restrict__ zn,
                                                       float* __restrict__ denom) {
    // LDS: A-tile [128][BK], B-tile [128][BK], chunk-XOR-swizzled within rows.
    __shared__ u16 As[128 * BK];
    __shared__ u16 Bs[128 * BK];
    const int tid  = threadIdx.x;
    const int w    = tid >> 6;
    const int lane = tid & 63;
    const int rowBase = blockIdx.y * 128;
    const int colBase = blockIdx.x * 128;
    const int wr = w >> 1, wc = w & 1;   // 2x2 wave grid, each wave: 64x64 out

    f32x4 acc[4][4] = {};

    // staging lane decomposition: 8 lanes per row (16B chunks), 8 rows / wave-issue
    const int lr = lane >> 3;                // row within 8-row group
    const int lc = (lane & 7) ^ lr;          // inverse-swizzled source chunk

    for (int kk = 0; kk < DIM; kk += BK) {
        #pragma unroll
        for (int t = 0; t < 4; ++t) {
            const int r0 = (t * 4 + w) * 8;  // uniform per wave
            gload16(zn + (size_t)(rowBase + r0 + lr) * DIM + kk + lc * 8, &As[r0 * BK]);
            gload16(zn + (size_t)(colBase + r0 + lr) * DIM + kk + lc * 8, &Bs[r0 * BK]);
        }
        __syncthreads();   // compiler drains vmcnt before s_barrier

        #pragma unroll
        for (int ks = 0; ks < 2; ++ks) {
            short8 af[4], bfv[4];
            #pragma unroll
            for (int mi = 0; mi < 4; ++mi) {
                const int r  = wr * 64 + mi * 16 + (lane & 15);
                const int ch = (ks * 4 + (lane >> 4)) ^ (r & 7);
                af[mi] = *reinterpret_cast<const short8*>(&As[r * BK + ch * 8]);
            }
            #pragma unroll
            for (int ni = 0; ni < 4; ++ni) {
                const int r  = wc * 64 + ni * 16 + (lane & 15);
                const int ch = (ks * 4 + (lane >> 4)) ^ (r & 7);
                bfv[ni] = *reinterpret_cast<const short8*>(&Bs[r * BK + ch * 8]);
            }
            #pragma unroll
            for (int mi = 0; mi < 4; ++mi)
                #pragma unroll
                for (int ni = 0; ni < 4; ++ni)
                    acc[mi][ni] = __builtin_amdgcn_mfma_f32_16x16x32_bf16(
                        af[mi], bfv[ni], acc[mi][ni], 0, 0, 0);
        }
        __syncthreads();
    }

    // epilogue: exp(2*sim), row-sum over this block's 128 cols, atomic into denom
    #pragma unroll
    for (int mi = 0; mi < 4; ++mi) {
        float rs[4] = {0.f, 0.f, 0.f, 0.f};
        #pragma unroll
        for (int ni = 0; ni < 4; ++ni)
            #pragma unroll
            for (int v = 0; v < 4; ++v)
                rs[v] += __expf(TEMP_INV * acc[mi][ni][v]);
        #pragma unroll
        for (int v = 0; v < 4; ++v) {
            float s = rs[v];
            s += __shfl_xor(s, 1);
            s += __shfl_xor(s, 2);
            s += __shfl_xor(s, 4);
            s += __shfl_xor(s, 8);
            if ((lane & 15) == 0)
                atomicAdd(&denom[rowBase + wr * 64 + mi * 16 + (lane >> 4) * 4 + v], s);
        }
    }
}

// ---------------- kernel 4: finalize loss -----------------------------------
__global__ __launch_bounds__(256) void finalize_k(const float* __restrict__ denom,
                                                  const float* __restrict__ pos,
                                                  const float* __restrict__ selfs,
                                                  float* __restrict__ out) {
    __shared__ float red[256];
    float s = 0.f;
    for (int i = threadIdx.x; i < NROWS; i += 256) {
        const float d = denom[i] - __expf(TEMP_INV * selfs[i]);  // drop diagonal
        s += logf(d) - TEMP_INV * pos[i];
    }
    red[threadIdx.x] = s;
    __syncthreads();
    #pragma unroll
    for (int m = 128; m; m >>= 1) {
        if (threadIdx.x < m) red[threadIdx.x] += red[threadIdx.x + m];
        __syncthreads();
    }
    if (threadIdx.x == 0) out[0] = red[0] * (1.0f / NROWS);
}

extern "C" void kernel_launch(void* const* d_in, const int* in_sizes, int n_in,
                              void* d_out, int out_size, void* d_ws, size_t ws_size,
                              hipStream_t stream) {
    const float* zi = (const float*)d_in[0];
    const float* zj = (const float*)d_in[1];
    float* out = (float*)d_out;

    // workspace layout: zn bf16 [8192][256] (4 MiB) | denom 8192 f32 | pos | self
    u16*   zn    = (u16*)d_ws;
    float* denom = (float*)((char*)d_ws + (size_t)NROWS * DIM * sizeof(u16));
    float* pos   = denom + NROWS;
    float* selfs = pos + NROWS;

    normalize_k<<<NROWS / 4, 256, 0, stream>>>(zi, zj, zn, denom);
    posself_k<<<NROWS / 4, 256, 0, stream>>>(zn, pos, selfs);
    gemm_exp_rowsum<<<dim3(64, 64), 256, 0, stream>>>(zn, denom);
    finalize_k<<<1, 256, 0, stream>>>(denom, pos, selfs, out);
}

// Round 2
// 87.688 us; speedup vs baseline: 1.1991x; 1.1991x over previous
//
#include <hip/hip_runtime.h>
#include <hip/hip_bf16.h>

typedef __attribute__((ext_vector_type(8))) short short8;
typedef __attribute__((ext_vector_type(4))) float f32x4;
typedef unsigned short u16;
typedef unsigned int u32;

#define NROWS 8192
#define HALF  4096
#define DIM   256
#define TEMP_INV 2.0f   // 1/temperature
#define BK 64
#define NBT 64           // 8192/128 block-tiles per side

__device__ __forceinline__ float bf2f(u16 u) {
    union { u32 i; float f; } c; c.i = ((u32)u) << 16; return c.f;
}
__device__ __forceinline__ u16 f2bf(float f) {
    union { float f; u32 i; } c; c.f = f;
    u32 lsb = (c.i >> 16) & 1;
    c.i += 0x7fffu + lsb;   // round-to-nearest-even
    return (u16)(c.i >> 16);
}

// ---------------- kernel 1: normalize rows, write bf16, zero denom ----------
__global__ __launch_bounds__(256) void normalize_k(const float* __restrict__ zi,
                                                   const float* __restrict__ zj,
                                                   u16* __restrict__ zn,
                                                   float* __restrict__ denom) {
    const int row  = blockIdx.x * 4 + (threadIdx.x >> 6);
    const int lane = threadIdx.x & 63;
    const float* src = (row < HALF) ? (zi + (size_t)row * DIM)
                                    : (zj + (size_t)(row - HALF) * DIM);
    float4 v = reinterpret_cast<const float4*>(src)[lane];
    float ss = v.x * v.x + v.y * v.y + v.z * v.z + v.w * v.w;
    #pragma unroll
    for (int m = 32; m; m >>= 1) ss += __shfl_xor(ss, m);
    const float inv = 1.0f / fmaxf(sqrtf(ss), 1e-8f);
    ushort4 o;
    o.x = f2bf(v.x * inv); o.y = f2bf(v.y * inv);
    o.z = f2bf(v.z * inv); o.w = f2bf(v.w * inv);
    reinterpret_cast<ushort4*>(zn + (size_t)row * DIM)[lane] = o;
    if (lane == 0) denom[row] = 0.0f;
}

// ---------------- kernel 2: triangular fused GEMM + exp + row/col sums ------
__device__ __forceinline__ void gload16(const void* g, void* lds) {
    __builtin_amdgcn_global_load_lds(
        (const __attribute__((address_space(1))) u32*)g,
        (__attribute__((address_space(3))) u32*)lds, 16, 0, 0);
}

__global__ __launch_bounds__(512) void gemm_exp_rowsum(const u16* __restrict__ zn,
                                                       float* __restrict__ denom,
                                                       float* __restrict__ pos,
                                                       float* __restrict__ selfs) {
    // Triangular block decode: b -> (by, bx), by <= bx
    const int b = blockIdx.x;
    int by = (int)((129.0f - sqrtf(129.0f * 129.0f - 8.0f * (float)b)) * 0.5f);
    while (by * (129 - by) / 2 > b) --by;
    while ((by + 1) * (129 - (by + 1)) / 2 <= b) ++by;
    const int bx = by + (b - by * (129 - by) / 2);
    const bool diag = (by == bx);

    const int rowBase = by * 128;
    const int colBase = bx * 128;

    __shared__ u16 As[2][128 * BK];
    __shared__ u16 Bs[2][128 * BK];

    const int tid  = threadIdx.x;
    const int w    = tid >> 6;      // 0..7
    const int lane = tid & 63;
    const int wr = w >> 2;          // 0..1  -> 64-row strip
    const int wc = w & 3;           // 0..3  -> 32-col strip

    f32x4 acc[4][2] = {};

    // staging decomposition: 8 lanes per row (16B chunks), 8 rows per issue
    const int lr = lane >> 3;           // row within 8-row group
    const int lc = (lane & 7) ^ lr;     // inverse-swizzled source chunk

    auto stage = [&](int buf, int kk) {
        #pragma unroll
        for (int s = 0; s < 2; ++s) {
            const int r0 = (w * 2 + s) * 8;   // wave-uniform
            gload16(zn + (size_t)(rowBase + r0 + lr) * DIM + kk + lc * 8,
                    &As[buf][r0 * BK]);
        }
        if (!diag) {
            #pragma unroll
            for (int s = 0; s < 2; ++s) {
                const int r0 = (w * 2 + s) * 8;
                gload16(zn + (size_t)(colBase + r0 + lr) * DIM + kk + lc * 8,
                        &Bs[buf][r0 * BK]);
            }
        }
    };

    auto compute = [&](int buf) {
        const u16* Bsrc = diag ? &As[buf][0] : &Bs[buf][0];
        #pragma unroll
        for (int ks = 0; ks < 2; ++ks) {
            short8 af[4], bfv[2];
            #pragma unroll
            for (int mi = 0; mi < 4; ++mi) {
                const int r  = wr * 64 + mi * 16 + (lane & 15);
                const int ch = (ks * 4 + (lane >> 4)) ^ (r & 7);
                af[mi] = *reinterpret_cast<const short8*>(&As[buf][r * BK + ch * 8]);
            }
            #pragma unroll
            for (int ni = 0; ni < 2; ++ni) {
                const int r  = wc * 32 + ni * 16 + (lane & 15);
                const int ch = (ks * 4 + (lane >> 4)) ^ (r & 7);
                bfv[ni] = *reinterpret_cast<const short8*>(&Bsrc[r * BK + ch * 8]);
            }
            #pragma unroll
            for (int mi = 0; mi < 4; ++mi)
                #pragma unroll
                for (int ni = 0; ni < 2; ++ni)
                    acc[mi][ni] = __builtin_amdgcn_mfma_f32_16x16x32_bf16(
                        af[mi], bfv[ni], acc[mi][ni], 0, 0, 0);
        }
    };

    // 2-phase pipeline: stage next while computing current, one sync per K-step
    stage(0, 0);
    __syncthreads();
    int cur = 0;
    #pragma unroll
    for (int t = 0; t < 3; ++t) {
        stage(cur ^ 1, (t + 1) * BK);
        compute(cur);
        __syncthreads();
        cur ^= 1;
    }
    compute(cur);

    // -------- epilogue --------
    // C/D layout: col = lane&15, row = (lane>>4)*4 + v
    float cs[2] = {0.f, 0.f};
    #pragma unroll
    for (int mi = 0; mi < 4; ++mi) {
        float rs[4] = {0.f, 0.f, 0.f, 0.f};
        #pragma unroll
        for (int ni = 0; ni < 2; ++ni)
            #pragma unroll
            for (int v = 0; v < 4; ++v) {
                const float e = __expf(TEMP_INV * acc[mi][ni][v]);
                rs[v] += e;
                cs[ni] += e;
            }
        #pragma unroll
        for (int v = 0; v < 4; ++v) {
            float s = rs[v];
            s += __shfl_xor(s, 1);
            s += __shfl_xor(s, 2);
            s += __shfl_xor(s, 4);
            s += __shfl_xor(s, 8);
            if ((lane & 15) == 0)
                atomicAdd(&denom[rowBase + wr * 64 + mi * 16 + (lane >> 4) * 4 + v], s);
        }
    }
    if (!diag) {
        // symmetric contribution: col sums of this block feed denom[col rows]
        #pragma unroll
        for (int ni = 0; ni < 2; ++ni) {
            float c = cs[ni];
            c += __shfl_xor(c, 16);
            c += __shfl_xor(c, 32);
            if (lane < 16)
                atomicAdd(&denom[colBase + wc * 32 + ni * 16 + lane], c);
        }
    }

    // diagonal extraction: selfs from diag blocks, pos from bx-by==32 blocks
    if (diag || bx - by == 32) {
        #pragma unroll
        for (int mi = 0; mi < 4; ++mi)
            #pragma unroll
            for (int ni = 0; ni < 2; ++ni)
                if (wr * 64 + mi * 16 == wc * 32 + ni * 16) {
                    #pragma unroll
                    for (int v = 0; v < 4; ++v)
                        if (((lane >> 4) * 4 + v) == (lane & 15)) {
                            const float val = acc[mi][ni][v];
                            const int g = rowBase + wr * 64 + mi * 16 + (lane & 15);
                            if (diag) selfs[g] = val;
                            else { pos[g] = val; pos[g + HALF] = val; }
                        }
                }
    }
}

// ---------------- kernel 3: finalize loss -----------------------------------
__global__ __launch_bounds__(256) void finalize_k(const float* __restrict__ denom,
                                                  const float* __restrict__ pos,
                                                  const float* __restrict__ selfs,
                                                  float* __restrict__ out) {
    __shared__ float red[256];
    float s = 0.f;
    for (int i = threadIdx.x; i < NROWS; i += 256) {
        const float d = denom[i] - __expf(TEMP_INV * selfs[i]);  // drop diagonal
        s += logf(d) - TEMP_INV * pos[i];
    }
    red[threadIdx.x] = s;
    __syncthreads();
    #pragma unroll
    for (int m = 128; m; m >>= 1) {
        if (threadIdx.x < m) red[threadIdx.x] += red[threadIdx.x + m];
        __syncthreads();
    }
    if (threadIdx.x == 0) out[0] = red[0] * (1.0f / NROWS);
}

extern "C" void kernel_launch(void* const* d_in, const int* in_sizes, int n_in,
                              void* d_out, int out_size, void* d_ws, size_t ws_size,
                              hipStream_t stream) {
    const float* zi = (const float*)d_in[0];
    const float* zj = (const float*)d_in[1];
    float* out = (float*)d_out;

    // workspace layout: zn bf16 [8192][256] (4 MiB) | denom 8192 f32 | pos | self
    u16*   zn    = (u16*)d_ws;
    float* denom = (float*)((char*)d_ws + (size_t)NROWS * DIM * sizeof(u16));
    float* pos   = denom + NROWS;
    float* selfs = pos + NROWS;

    normalize_k<<<NROWS / 4, 256, 0, stream>>>(zi, zj, zn, denom);
    gemm_exp_rowsum<<<NBT * (NBT + 1) / 2, 512, 0, stream>>>(zn, denom, pos, selfs);
    finalize_k<<<1, 256, 0, stream>>>(denom, pos, selfs, out);
}

// Round 3
// 75.319 us; speedup vs baseline: 1.3960x; 1.1642x over previous
//
#include <hip/hip_runtime.h>
#include <hip/hip_bf16.h>

typedef __attribute__((ext_vector_type(8))) short short8;
typedef __attribute__((ext_vector_type(4))) float f32x4;
typedef unsigned short u16;
typedef unsigned int u32;

#define NROWS 8192
#define HALF  4096
#define DIM   256
#define TEMP_INV 2.0f   // 1/temperature
#define BK 64
#define NBT 32           // 8192/256 block-tiles per side
#define NBLK (NBT * (NBT + 1) / 2)   // 528 triangular blocks

#define BARRIER() asm volatile("s_barrier" ::: "memory")
#define WAITV(n)  asm volatile("s_waitcnt vmcnt(" #n ")" ::: "memory")

__device__ __forceinline__ u16 f2bf(float f) {
    union { float f; u32 i; } c; c.f = f;
    u32 lsb = (c.i >> 16) & 1;
    c.i += 0x7fffu + lsb;   // round-to-nearest-even
    return (u16)(c.i >> 16);
}

// ---------------- kernel 1: normalize rows, write bf16, zero denom ----------
__global__ __launch_bounds__(256) void normalize_k(const float* __restrict__ zi,
                                                   const float* __restrict__ zj,
                                                   u16* __restrict__ zn,
                                                   float* __restrict__ denom) {
    const int row  = blockIdx.x * 4 + (threadIdx.x >> 6);
    const int lane = threadIdx.x & 63;
    const float* src = (row < HALF) ? (zi + (size_t)row * DIM)
                                    : (zj + (size_t)(row - HALF) * DIM);
    float4 v = reinterpret_cast<const float4*>(src)[lane];
    float ss = v.x * v.x + v.y * v.y + v.z * v.z + v.w * v.w;
    #pragma unroll
    for (int m = 32; m; m >>= 1) ss += __shfl_xor(ss, m);
    const float inv = 1.0f / fmaxf(sqrtf(ss), 1e-8f);
    ushort4 o;
    o.x = f2bf(v.x * inv); o.y = f2bf(v.y * inv);
    o.z = f2bf(v.z * inv); o.w = f2bf(v.w * inv);
    reinterpret_cast<ushort4*>(zn + (size_t)row * DIM)[lane] = o;
    if (lane == 0) denom[row] = 0.0f;
}

// ---------------- kernel 2: 256^2-tile triangular GEMM + exp + row/col sums -
__device__ __forceinline__ void gload16(const void* g, void* lds) {
    __builtin_amdgcn_global_load_lds(
        (const __attribute__((address_space(1))) u32*)g,
        (__attribute__((address_space(3))) u32*)lds, 16, 0, 0);
}

__global__ __launch_bounds__(512) void gemm_exp_rowsum(const u16* __restrict__ zn,
                                                       float* __restrict__ denom,
                                                       float* __restrict__ pos) {
    // Triangular block decode: b -> (by, bx), by <= bx < 32
    const int b = blockIdx.x;
    int by = (int)((65.0f - sqrtf(65.0f * 65.0f - 8.0f * (float)b)) * 0.5f);
    while (by * (65 - by) / 2 > b) --by;
    while ((by + 1) * (64 - by) / 2 <= b) ++by;
    const int bx = by + (b - by * (65 - by) / 2);
    const bool diag  = (by == bx);
    const bool isPos = (bx - by == 16);

    const int rowBase = by * 256;
    const int colBase = bx * 256;

    __shared__ u16 As[2][256 * BK];   // 32 KiB each buf
    __shared__ u16 Bs[2][256 * BK];   // 128 KiB total LDS

    const int tid  = threadIdx.x;
    const int w    = tid >> 6;      // 0..7
    const int lane = tid & 63;
    const int wr = w >> 2;          // 0..1  -> 128-row strip
    const int wc = w & 3;           // 0..3  -> 64-col strip

    f32x4 acc[8][4] = {};

    // staging lane decomposition: 8 lanes/row (16B chunks), 8 rows/issue,
    // chunk-XOR swizzle: LDS chunk ch holds source chunk ch ^ (row&7)
    const int lr = lane >> 3;
    const int lc = (lane & 7) ^ lr;

    auto stage = [&](int buf, int kk) {
        #pragma unroll
        for (int s = 0; s < 4; ++s) {
            const int r0 = w * 32 + s * 8;   // wave-uniform
            gload16(zn + (size_t)(rowBase + r0 + lr) * DIM + kk + lc * 8,
                    &As[buf][r0 * BK]);
        }
        #pragma unroll
        for (int s = 0; s < 4; ++s) {
            const int r0 = w * 32 + s * 8;
            gload16(zn + (size_t)(colBase + r0 + lr) * DIM + kk + lc * 8,
                    &Bs[buf][r0 * BK]);
        }
    };

    auto compute = [&](int buf) {
        #pragma unroll
        for (int ks = 0; ks < 2; ++ks) {
            short8 af[8], bfv[4];
            #pragma unroll
            for (int mi = 0; mi < 8; ++mi) {
                const int r  = wr * 128 + mi * 16 + (lane & 15);
                const int ch = (ks * 4 + (lane >> 4)) ^ (r & 7);
                af[mi] = *reinterpret_cast<const short8*>(&As[buf][r * BK + ch * 8]);
            }
            #pragma unroll
            for (int ni = 0; ni < 4; ++ni) {
                const int r  = wc * 64 + ni * 16 + (lane & 15);
                const int ch = (ks * 4 + (lane >> 4)) ^ (r & 7);
                bfv[ni] = *reinterpret_cast<const short8*>(&Bs[buf][r * BK + ch * 8]);
            }
            __builtin_amdgcn_s_setprio(1);
            #pragma unroll
            for (int mi = 0; mi < 8; ++mi)
                #pragma unroll
                for (int ni = 0; ni < 4; ++ni)
                    acc[mi][ni] = __builtin_amdgcn_mfma_f32_16x16x32_bf16(
                        af[mi], bfv[ni], acc[mi][ni], 0, 0, 0);
            __builtin_amdgcn_s_setprio(0);
        }
    };

    // K = 256 = 4 steps of BK=64; double-buffered, counted-vmcnt pipeline.
    // Each stage() = 8 global_load_lds per wave.
    stage(0, 0);
    stage(1, BK);
    WAITV(8);  BARRIER();   // K0 landed everywhere (K1's 8 may be in flight)
    compute(0);
    BARRIER();              // all waves done reading buf0
    stage(0, 2 * BK);
    WAITV(8);  BARRIER();   // K1 landed (K2's 8 in flight)
    compute(1);
    BARRIER();
    stage(1, 3 * BK);
    WAITV(8);  BARRIER();   // K2 landed (K3's 8 in flight)
    compute(0);
    WAITV(0);  BARRIER();   // K3 landed
    compute(1);

    // -------- epilogue --------
    // C/D layout: col = lane&15, row = (lane>>4)*4 + v
    float cs[4] = {0.f, 0.f, 0.f, 0.f};
    #pragma unroll
    for (int mi = 0; mi < 8; ++mi) {
        float rs[4] = {0.f, 0.f, 0.f, 0.f};
        #pragma unroll
        for (int ni = 0; ni < 4; ++ni)
            #pragma unroll
            for (int v = 0; v < 4; ++v) {
                const int R = wr * 128 + mi * 16 + (lane >> 4) * 4 + v;
                const int C = wc * 64 + ni * 16 + (lane & 15);
                float e = __expf(TEMP_INV * acc[mi][ni][v]);
                if (diag && R == C) e = 0.f;   // exclude self-similarity
                rs[v] += e;
                cs[ni] += e;
            }
        #pragma unroll
        for (int v = 0; v < 4; ++v) {
            float s = rs[v];
            s += __shfl_xor(s, 1);
            s += __shfl_xor(s, 2);
            s += __shfl_xor(s, 4);
            s += __shfl_xor(s, 8);
            if ((lane & 15) == 0)
                atomicAdd(&denom[rowBase + wr * 128 + mi * 16 + (lane >> 4) * 4 + v], s);
        }
    }
    if (!diag) {
        // symmetric contribution: col sums feed denom[col]
        #pragma unroll
        for (int ni = 0; ni < 4; ++ni) {
            float c = cs[ni];
            c += __shfl_xor(c, 16);
            c += __shfl_xor(c, 32);
            if (lane < 16)
                atomicAdd(&denom[colBase + wc * 64 + ni * 16 + lane], c);
        }
    }
    if (isPos) {
        // tile-diagonal elements are sim(i, i+HALF)
        #pragma unroll
        for (int mi = 0; mi < 8; ++mi)
            #pragma unroll
            for (int ni = 0; ni < 4; ++ni)
                #pragma unroll
                for (int v = 0; v < 4; ++v) {
                    const int R = wr * 128 + mi * 16 + (lane >> 4) * 4 + v;
                    const int C = wc * 64 + ni * 16 + (lane & 15);
                    if (R == C) {
                        const float val = acc[mi][ni][v];
                        pos[rowBase + R] = val;
                        pos[rowBase + R + HALF] = val;
                    }
                }
    }
}

// ---------------- kernel 3: finalize loss -----------------------------------
__global__ __launch_bounds__(256) void finalize_k(const float* __restrict__ denom,
                                                  const float* __restrict__ pos,
                                                  float* __restrict__ out) {
    __shared__ float red[256];
    float s = 0.f;
    for (int i = threadIdx.x; i < NROWS; i += 256)
        s += logf(denom[i]) - TEMP_INV * pos[i];
    red[threadIdx.x] = s;
    __syncthreads();
    #pragma unroll
    for (int m = 128; m; m >>= 1) {
        if (threadIdx.x < m) red[threadIdx.x] += red[threadIdx.x + m];
        __syncthreads();
    }
    if (threadIdx.x == 0) out[0] = red[0] * (1.0f / NROWS);
}

extern "C" void kernel_launch(void* const* d_in, const int* in_sizes, int n_in,
                              void* d_out, int out_size, void* d_ws, size_t ws_size,
                              hipStream_t stream) {
    const float* zi = (const float*)d_in[0];
    const float* zj = (const float*)d_in[1];
    float* out = (float*)d_out;

    // workspace: zn bf16 [8192][256] (4 MiB) | denom 8192 f32 | pos 8192 f32
    u16*   zn    = (u16*)d_ws;
    float* denom = (float*)((char*)d_ws + (size_t)NROWS * DIM * sizeof(u16));
    float* pos   = denom + NROWS;

    normalize_k<<<NROWS / 4, 256, 0, stream>>>(zi, zj, zn, denom);
    gemm_exp_rowsum<<<NBLK, 512, 0, stream>>>(zn, denom, pos);
    finalize_k<<<1, 256, 0, stream>>>(denom, pos, out);
}

// Round 4
// 63.281 us; speedup vs baseline: 1.6616x; 1.1902x over previous
//
#include <hip/hip_runtime.h>
#include <hip/hip_bf16.h>

typedef __attribute__((ext_vector_type(8))) short short8;
typedef __attribute__((ext_vector_type(4))) float f32x4;
typedef unsigned short u16;
typedef unsigned int u32;

#define NROWS 8192
#define HALF  4096
#define DIM   256
#define TEMP_INV 2.0f   // 1/temperature
#define BK 32
#define NBT 64                        // 8192/128 tiles per side
#define NBLK (NBT * (NBT + 1) / 2)    // 2080 triangular blocks

#define BARRIER() asm volatile("s_barrier" ::: "memory")
#define WAITV(n)  asm volatile("s_waitcnt vmcnt(" #n ")" ::: "memory")

__device__ __forceinline__ u16 f2bf(float f) {
    union { float f; u32 i; } c; c.f = f;
    u32 lsb = (c.i >> 16) & 1;
    c.i += 0x7fffu + lsb;   // round-to-nearest-even
    return (u16)(c.i >> 16);
}

// ---------------- kernel 1: normalize rows, write bf16, zero denom ----------
__global__ __launch_bounds__(256) void normalize_k(const float* __restrict__ zi,
                                                   const float* __restrict__ zj,
                                                   u16* __restrict__ zn,
                                                   float* __restrict__ denom) {
    const int row  = blockIdx.x * 4 + (threadIdx.x >> 6);
    const int lane = threadIdx.x & 63;
    const float* src = (row < HALF) ? (zi + (size_t)row * DIM)
                                    : (zj + (size_t)(row - HALF) * DIM);
    float4 v = reinterpret_cast<const float4*>(src)[lane];
    float ss = v.x * v.x + v.y * v.y + v.z * v.z + v.w * v.w;
    #pragma unroll
    for (int m = 32; m; m >>= 1) ss += __shfl_xor(ss, m);
    const float inv = 1.0f / fmaxf(sqrtf(ss), 1e-8f);
    ushort4 o;
    o.x = f2bf(v.x * inv); o.y = f2bf(v.y * inv);
    o.z = f2bf(v.z * inv); o.w = f2bf(v.w * inv);
    reinterpret_cast<ushort4*>(zn + (size_t)row * DIM)[lane] = o;
    if (lane == 0) denom[row] = 0.0f;
}

// ---------------- kernel 2: 128^2-tile triangular GEMM + exp + row/col sums -
__device__ __forceinline__ void gload16(const void* g, void* lds) {
    __builtin_amdgcn_global_load_lds(
        (const __attribute__((address_space(1))) u32*)g,
        (__attribute__((address_space(3))) u32*)lds, 16, 0, 0);
}

__global__ __launch_bounds__(256, 3) void gemm_exp_rowsum(const u16* __restrict__ zn,
                                                          float* __restrict__ denom,
                                                          float* __restrict__ pos) {
    // XCD-aware bijective swizzle (2080 = 8 * 260): consecutive decoded b on
    // one XCD share the A row-panel -> per-XCD L2 locality.
    const int b0 = blockIdx.x;
    const int b  = (b0 & 7) * (NBLK / 8) + (b0 >> 3);
    // Triangular decode: b -> (by, bx), by <= bx < 64
    int by = (int)((129.0f - sqrtf(129.0f * 129.0f - 8.0f * (float)b)) * 0.5f);
    while (by * (129 - by) / 2 > b) --by;
    while ((by + 1) * (129 - (by + 1)) / 2 <= b) ++by;
    const int bx = by + (b - by * (129 - by) / 2);
    const bool diag  = (by == bx);
    const bool isPos = (bx - by == 32);

    const int rowBase = by * 128;
    const int colBase = bx * 128;

    __shared__ u16 As[2][128 * BK];   // 8 KiB per buf
    __shared__ u16 Bs[2][128 * BK];   // total LDS 32 KiB

    const int tid  = threadIdx.x;
    const int w    = tid >> 6;      // 0..3
    const int lane = tid & 63;
    const int wr = w >> 1;          // 0..1 -> 64-row strip
    const int wc = w & 1;           // 0..1 -> 64-col strip

    f32x4 acc[4][4] = {};

    // ---- staging: rows are 64B (BK=32). LDS dest linear; source chunk
    // pre-swizzled with key(row) = (row>>1)&3 so ds_read is ~2-way max.
    const int lr = lane >> 2;                       // 16 rows / 1KB issue
    const int lc = (lane & 3) ^ ((lane >> 3) & 3);  // inverse-swizzled chunk

    auto stage = [&](int buf, int kk) {
        #pragma unroll
        for (int s = 0; s < 2; ++s) {
            const int r0 = w * 32 + s * 16;   // wave-uniform
            gload16(zn + (size_t)(rowBase + r0 + lr) * DIM + kk + lc * 8,
                    &As[buf][r0 * BK]);
        }
        #pragma unroll
        for (int s = 0; s < 2; ++s) {
            const int r0 = w * 32 + s * 16;
            gload16(zn + (size_t)(colBase + r0 + lr) * DIM + kk + lc * 8,
                    &Bs[buf][r0 * BK]);
        }
    };

    // ds_read bases: chunk key depends only on lane&15 -> mi/ni fold to
    // compile-time offsets (mi*1024), buf to +8192.
    const int chunk = ((lane >> 4) ^ (((lane & 15) >> 1) & 3)) * 16;
    const char* Ab = (const char*)&As[0][0] + (wr * 64 + (lane & 15)) * 64 + chunk;
    const char* Bb = (const char*)&Bs[0][0] + (wc * 64 + (lane & 15)) * 64 + chunk;

    auto compute = [&](int buf) {
        short8 af[4], bfr[4];
        #pragma unroll
        for (int mi = 0; mi < 4; ++mi)
            af[mi] = *reinterpret_cast<const short8*>(Ab + buf * 8192 + mi * 1024);
        #pragma unroll
        for (int ni = 0; ni < 4; ++ni)
            bfr[ni] = *reinterpret_cast<const short8*>(Bb + buf * 8192 + ni * 1024);
        __builtin_amdgcn_s_setprio(1);
        #pragma unroll
        for (int mi = 0; mi < 4; ++mi)
            #pragma unroll
            for (int ni = 0; ni < 4; ++ni)
                acc[mi][ni] = __builtin_amdgcn_mfma_f32_16x16x32_bf16(
                    af[mi], bfr[ni], acc[mi][ni], 0, 0, 0);
        __builtin_amdgcn_s_setprio(0);
    };

    // K = 256 = 8 steps of BK=32; double-buffered, counted-vmcnt (never 0
    // mid-loop). Each stage() = 4 global_load_lds per wave.
    stage(0, 0);
    stage(1, BK);
    WAITV(4);  BARRIER();           // buf0 ready (buf1's 4 in flight)
    #pragma unroll
    for (int t = 0; t < 8; ++t) {
        const int cur = t & 1;
        compute(cur);
        if (t < 6) {
            BARRIER();              // all waves done reading buf cur
            stage(cur, (t + 2) * BK);
            WAITV(4);  BARRIER();   // buf cur^1 ready (new 4 in flight)
        } else if (t == 6) {
            WAITV(0);  BARRIER();   // last buffer fully landed
        }
    }

    // -------- epilogue --------
    // C/D layout: col = lane&15, row = (lane>>4)*4 + v
    float cs[4] = {0.f, 0.f, 0.f, 0.f};
    #pragma unroll
    for (int mi = 0; mi < 4; ++mi) {
        float rs[4] = {0.f, 0.f, 0.f, 0.f};
        #pragma unroll
        for (int ni = 0; ni < 4; ++ni)
            #pragma unroll
            for (int v = 0; v < 4; ++v) {
                const int R = wr * 64 + mi * 16 + (lane >> 4) * 4 + v;
                const int C = wc * 64 + ni * 16 + (lane & 15);
                float e = __expf(TEMP_INV * acc[mi][ni][v]);
                if (diag && R == C) e = 0.f;   // exclude self-similarity
                rs[v] += e;
                cs[ni] += e;
            }
        #pragma unroll
        for (int v = 0; v < 4; ++v) {
            float s = rs[v];
            s += __shfl_xor(s, 1);
            s += __shfl_xor(s, 2);
            s += __shfl_xor(s, 4);
            s += __shfl_xor(s, 8);
            if ((lane & 15) == 0)
                atomicAdd(&denom[rowBase + wr * 64 + mi * 16 + (lane >> 4) * 4 + v], s);
        }
    }
    if (!diag) {
        // symmetric contribution: col sums feed denom[col]
        #pragma unroll
        for (int ni = 0; ni < 4; ++ni) {
            float c = cs[ni];
            c += __shfl_xor(c, 16);
            c += __shfl_xor(c, 32);
            if (lane < 16)
                atomicAdd(&denom[colBase + wc * 64 + ni * 16 + lane], c);
        }
    }
    if (isPos) {
        // tile-diagonal elements are sim(i, i+HALF)
        #pragma unroll
        for (int mi = 0; mi < 4; ++mi)
            #pragma unroll
            for (int ni = 0; ni < 4; ++ni)
                #pragma unroll
                for (int v = 0; v < 4; ++v) {
                    const int R = wr * 64 + mi * 16 + (lane >> 4) * 4 + v;
                    const int C = wc * 64 + ni * 16 + (lane & 15);
                    if (R == C) {
                        const float val = acc[mi][ni][v];
                        pos[rowBase + R] = val;
                        pos[rowBase + R + HALF] = val;
                    }
                }
    }
}

// ---------------- kernel 3: finalize loss -----------------------------------
__global__ __launch_bounds__(512) void finalize_k(const float* __restrict__ denom,
                                                  const float* __restrict__ pos,
                                                  float* __restrict__ out) {
    __shared__ float red[512];
    float s = 0.f;
    for (int i = threadIdx.x; i < NROWS; i += 512)
        s += logf(denom[i]) - TEMP_INV * pos[i];
    red[threadIdx.x] = s;
    __syncthreads();
    #pragma unroll
    for (int m = 256; m; m >>= 1) {
        if (threadIdx.x < m) red[threadIdx.x] += red[threadIdx.x + m];
        __syncthreads();
    }
    if (threadIdx.x == 0) out[0] = red[0] * (1.0f / NROWS);
}

extern "C" void kernel_launch(void* const* d_in, const int* in_sizes, int n_in,
                              void* d_out, int out_size, void* d_ws, size_t ws_size,
                              hipStream_t stream) {
    const float* zi = (const float*)d_in[0];
    const float* zj = (const float*)d_in[1];
    float* out = (float*)d_out;

    // workspace: zn bf16 [8192][256] (4 MiB) | denom 8192 f32 | pos 8192 f32
    u16*   zn    = (u16*)d_ws;
    float* denom = (float*)((char*)d_ws + (size_t)NROWS * DIM * sizeof(u16));
    float* pos   = denom + NROWS;

    normalize_k<<<NROWS / 4, 256, 0, stream>>>(zi, zj, zn, denom);
    gemm_exp_rowsum<<<NBLK, 256, 0, stream>>>(zn, denom, pos);
    finalize_k<<<1, 512, 0, stream>>>(denom, pos, out);
}

// Round 5
// 51.414 us; speedup vs baseline: 2.0451x; 1.2308x over previous
//
#include <hip/hip_runtime.h>
#include <hip/hip_bf16.h>

typedef __attribute__((ext_vector_type(8))) short short8;
typedef __attribute__((ext_vector_type(4))) float f32x4;
typedef unsigned short u16;
typedef unsigned int u32;

#define NROWS 8192
#define HALF  4096
#define DIM   256
#define TEMP_INV 2.0f   // 1/temperature
#define BK 32
#define NBT 64                        // 8192/128 tiles per side
#define NBLK (NBT * (NBT + 1) / 2)    // 2080 triangular blocks
#define NSLAB 128                     // 64 tiles * 2 wave-halves

#define BARRIER() asm volatile("s_barrier" ::: "memory")
#define WAITV(n)  asm volatile("s_waitcnt vmcnt(" #n ")" ::: "memory")

__device__ __forceinline__ u16 f2bf(float f) {
    union { float f; u32 i; } c; c.f = f;
    u32 lsb = (c.i >> 16) & 1;
    c.i += 0x7fffu + lsb;   // round-to-nearest-even
    return (u16)(c.i >> 16);
}

// ---------------- kernel 1: normalize rows, write bf16 ----------------------
__global__ __launch_bounds__(256) void normalize_k(const float* __restrict__ zi,
                                                   const float* __restrict__ zj,
                                                   u16* __restrict__ zn) {
    const int row  = blockIdx.x * 4 + (threadIdx.x >> 6);
    const int lane = threadIdx.x & 63;
    const float* src = (row < HALF) ? (zi + (size_t)row * DIM)
                                    : (zj + (size_t)(row - HALF) * DIM);
    float4 v = reinterpret_cast<const float4*>(src)[lane];
    float ss = v.x * v.x + v.y * v.y + v.z * v.z + v.w * v.w;
    #pragma unroll
    for (int m = 32; m; m >>= 1) ss += __shfl_xor(ss, m);
    const float inv = 1.0f / fmaxf(sqrtf(ss), 1e-8f);
    ushort4 o;
    o.x = f2bf(v.x * inv); o.y = f2bf(v.y * inv);
    o.z = f2bf(v.z * inv); o.w = f2bf(v.w * inv);
    reinterpret_cast<ushort4*>(zn + (size_t)row * DIM)[lane] = o;
}

// ---------------- kernel 2: 128^2-tile triangular GEMM + exp + slab sums ----
// slab layout: [NSLAB][NROWS] f32. Row-side partial sums for global row g go
// to slab[bx*2 + wc][g]; col-side (symmetric) partials to slab[by*2 + wr][g].
// Triangular coverage => every slot written by exactly ONE wave: no atomics,
// no zero-init.
__device__ __forceinline__ void gload16(const void* g, void* lds) {
    __builtin_amdgcn_global_load_lds(
        (const __attribute__((address_space(1))) u32*)g,
        (__attribute__((address_space(3))) u32*)lds, 16, 0, 0);
}

__global__ __launch_bounds__(256, 3) void gemm_exp_rowsum(const u16* __restrict__ zn,
                                                          float* __restrict__ slab,
                                                          float* __restrict__ pos) {
    // XCD-aware bijective swizzle (2080 = 8 * 260)
    const int b0 = blockIdx.x;
    const int b  = (b0 & 7) * (NBLK / 8) + (b0 >> 3);
    // Triangular decode: b -> (by, bx), by <= bx < 64
    int by = (int)((129.0f - sqrtf(129.0f * 129.0f - 8.0f * (float)b)) * 0.5f);
    while (by * (129 - by) / 2 > b) --by;
    while ((by + 1) * (129 - (by + 1)) / 2 <= b) ++by;
    const int bx = by + (b - by * (129 - by) / 2);
    const bool diag  = (by == bx);
    const bool isPos = (bx - by == 32);

    const int rowBase = by * 128;
    const int colBase = bx * 128;

    __shared__ u16 As[2][128 * BK];   // 8 KiB per buf
    __shared__ u16 Bs[2][128 * BK];   // total LDS 32 KiB

    const int tid  = threadIdx.x;
    const int w    = tid >> 6;      // 0..3
    const int lane = tid & 63;
    const int wr = w >> 1;          // 0..1 -> 64-row strip
    const int wc = w & 1;           // 0..1 -> 64-col strip

    f32x4 acc[4][4] = {};

    // staging: LDS dest linear; source chunk pre-swizzled, key(row)=(row>>1)&3
    const int lr = lane >> 2;
    const int lc = (lane & 3) ^ ((lane >> 3) & 3);

    auto stage = [&](int buf, int kk) {
        #pragma unroll
        for (int s = 0; s < 2; ++s) {
            const int r0 = w * 32 + s * 16;   // wave-uniform
            gload16(zn + (size_t)(rowBase + r0 + lr) * DIM + kk + lc * 8,
                    &As[buf][r0 * BK]);
        }
        #pragma unroll
        for (int s = 0; s < 2; ++s) {
            const int r0 = w * 32 + s * 16;
            gload16(zn + (size_t)(colBase + r0 + lr) * DIM + kk + lc * 8,
                    &Bs[buf][r0 * BK]);
        }
    };

    // ds_read bases: chunk key depends only on lane&15
    const int chunk = ((lane >> 4) ^ (((lane & 15) >> 1) & 3)) * 16;
    const char* Ab = (const char*)&As[0][0] + (wr * 64 + (lane & 15)) * 64 + chunk;
    const char* Bb = (const char*)&Bs[0][0] + (wc * 64 + (lane & 15)) * 64 + chunk;

    auto compute = [&](int buf) {
        short8 af[4], bfr[4];
        #pragma unroll
        for (int mi = 0; mi < 4; ++mi)
            af[mi] = *reinterpret_cast<const short8*>(Ab + buf * 8192 + mi * 1024);
        #pragma unroll
        for (int ni = 0; ni < 4; ++ni)
            bfr[ni] = *reinterpret_cast<const short8*>(Bb + buf * 8192 + ni * 1024);
        __builtin_amdgcn_s_setprio(1);
        #pragma unroll
        for (int mi = 0; mi < 4; ++mi)
            #pragma unroll
            for (int ni = 0; ni < 4; ++ni)
                acc[mi][ni] = __builtin_amdgcn_mfma_f32_16x16x32_bf16(
                    af[mi], bfr[ni], acc[mi][ni], 0, 0, 0);
        __builtin_amdgcn_s_setprio(0);
    };

    // K = 256 = 8 steps of BK=32; double-buffered, counted-vmcnt.
    stage(0, 0);
    stage(1, BK);
    WAITV(4);  BARRIER();           // buf0 ready (buf1's 4 in flight)
    #pragma unroll
    for (int t = 0; t < 8; ++t) {
        const int cur = t & 1;
        compute(cur);
        if (t < 6) {
            BARRIER();              // all waves done reading buf cur
            stage(cur, (t + 2) * BK);
            WAITV(4);  BARRIER();   // buf cur^1 ready (new 4 in flight)
        } else if (t == 6) {
            WAITV(0);  BARRIER();   // last buffer fully landed
        }
    }

    // -------- epilogue: no atomics, unique-slot coalesced stores --------
    // C/D layout: col = lane&15, row = (lane>>4)*4 + v
    float cs[4] = {0.f, 0.f, 0.f, 0.f};
    float* rowSlot = slab + (size_t)(bx * 2 + wc) * NROWS + rowBase + wr * 64;
    #pragma unroll
    for (int mi = 0; mi < 4; ++mi) {
        f32x4 rs = {0.f, 0.f, 0.f, 0.f};
        #pragma unroll
        for (int ni = 0; ni < 4; ++ni)
            #pragma unroll
            for (int v = 0; v < 4; ++v) {
                const int R = wr * 64 + mi * 16 + (lane >> 4) * 4 + v;
                const int C = wc * 64 + ni * 16 + (lane & 15);
                float e = __expf(TEMP_INV * acc[mi][ni][v]);
                if (diag && R == C) e = 0.f;   // exclude self-similarity
                rs[v] += e;
                cs[ni] += e;
            }
        // allreduce each rs[v] across the 16-lane group -> every lane holds
        // the float4 of row sums for rows mi*16 + (lane>>4)*4 + 0..3
        #pragma unroll
        for (int v = 0; v < 4; ++v) {
            float s = rs[v];
            s += __shfl_xor(s, 1);
            s += __shfl_xor(s, 2);
            s += __shfl_xor(s, 4);
            s += __shfl_xor(s, 8);
            rs[v] = s;
        }
        if ((lane & 15) == 0)   // 4 lanes (g=0..3) -> one coalesced 64B store
            *reinterpret_cast<f32x4*>(rowSlot + mi * 16 + (lane >> 4) * 4) = rs;
    }
    if (!diag) {
        // symmetric contribution: col sums -> slab[by*2 + wr][colBase + c]
        float* colSlot = slab + (size_t)(by * 2 + wr) * NROWS + colBase + wc * 64;
        #pragma unroll
        for (int ni = 0; ni < 4; ++ni) {
            float c = cs[ni];
            c += __shfl_xor(c, 16);
            c += __shfl_xor(c, 32);
            if (lane < 16)
                colSlot[ni * 16 + lane] = c;
        }
    }
    if (isPos) {
        // tile-diagonal elements are sim(i, i+HALF)
        #pragma unroll
        for (int mi = 0; mi < 4; ++mi)
            #pragma unroll
            for (int ni = 0; ni < 4; ++ni)
                #pragma unroll
                for (int v = 0; v < 4; ++v) {
                    const int R = wr * 64 + mi * 16 + (lane >> 4) * 4 + v;
                    const int C = wc * 64 + ni * 16 + (lane & 15);
                    if (R == C) {
                        const float val = acc[mi][ni][v];
                        pos[rowBase + R] = val;
                        pos[rowBase + R + HALF] = val;
                    }
                }
    }
}

// ---------------- kernel 3: reduce slab, finalize loss ----------------------
__global__ __launch_bounds__(256) void finalize_k(const float* __restrict__ slab,
                                                  const float* __restrict__ pos,
                                                  float* __restrict__ out) {
    const int row = blockIdx.x * 256 + threadIdx.x;
    float d = 0.f;
    #pragma unroll 8
    for (int j = 0; j < NSLAB; ++j)
        d += slab[(size_t)j * NROWS + row];    // coalesced across threads
    float s = logf(d) - TEMP_INV * pos[row];
    __shared__ float red[256];
    red[threadIdx.x] = s;
    __syncthreads();
    #pragma unroll
    for (int m = 128; m; m >>= 1) {
        if (threadIdx.x < m) red[threadIdx.x] += red[threadIdx.x + m];
        __syncthreads();
    }
    if (threadIdx.x == 0) atomicAdd(out, red[0] * (1.0f / NROWS));
}

extern "C" void kernel_launch(void* const* d_in, const int* in_sizes, int n_in,
                              void* d_out, int out_size, void* d_ws, size_t ws_size,
                              hipStream_t stream) {
    const float* zi = (const float*)d_in[0];
    const float* zj = (const float*)d_in[1];
    float* out = (float*)d_out;

    // workspace: zn bf16 [8192][256] (4 MiB) | slab f32 [128][8192] (4 MiB)
    //            | pos f32 [8192] (32 KiB)
    u16*   zn   = (u16*)d_ws;
    float* slab = (float*)((char*)d_ws + (size_t)NROWS * DIM * sizeof(u16));
    float* pos  = slab + (size_t)NSLAB * NROWS;

    hipMemsetAsync(d_out, 0, sizeof(float), stream);
    normalize_k<<<NROWS / 4, 256, 0, stream>>>(zi, zj, zn);
    gemm_exp_rowsum<<<NBLK, 256, 0, stream>>>(zn, slab, pos);
    finalize_k<<<NROWS / 256, 256, 0, stream>>>(slab, pos, out);
}